// Round 3
// baseline (255.012 us; speedup 1.0000x reference)
//
#include <hip/hip_runtime.h>
#include <math.h>

// Problem constants (B=4, S=2048, D_MODEL=512, H=8, DQ=64)
#define BATCH 4
#define SEQ   2048
#define DM    512
#define NH    8
#define DQ    64
#define BS    (BATCH*SEQ)     // 8192 rows
#define APAD  72              // padded tile stride in gemms

// q pre-scale: 1/sqrt(64) * log2(e), so softmax uses native 2^x (v_exp_f32)
#define QSCALE 0.18033688011112042f

typedef short  short8   __attribute__((ext_vector_type(8)));
typedef float  floatx4  __attribute__((ext_vector_type(4)));
typedef float  floatx16 __attribute__((ext_vector_type(16)));
typedef unsigned short ushort8 __attribute__((ext_vector_type(8)));
typedef unsigned uintx2 __attribute__((ext_vector_type(2)));
typedef unsigned uintx4 __attribute__((ext_vector_type(4)));

// cheap bf16: round-half-up (1 add + shift). Ties-only delta vs RNE.
__device__ __forceinline__ unsigned short f2bf(float f) {
    return (unsigned short)((__float_as_uint(f) + 0x8000u) >> 16);
}
// pack two floats -> two bf16 in one u32 (lo = a, hi = b): 2 adds + 1 v_perm
__device__ __forceinline__ unsigned pack2bf(float a, float b) {
    unsigned ua = __float_as_uint(a) + 0x8000u;
    unsigned ub = __float_as_uint(b) + 0x8000u;
    return __builtin_amdgcn_perm(ub, ua, 0x07060302u);  // {ub[3],ub[2],ua[3],ua[2]}
}

// ---------------------------------------------------------------------------
// convert_w: pack weights to bf16 B^T layout [n][k].
//   which 0..2: wt[which][h*64+d][dd] = W[h][dd][d]  (qkv projections)
//   which 3:    wo[o][c] = Wout[o][c]                 (already B^T)
// grid (256, 4).
// ---------------------------------------------------------------------------
__global__ __launch_bounds__(256) void convert_w_kernel(
    const float* __restrict__ Wq, const float* __restrict__ Wk,
    const float* __restrict__ Wv, const float* __restrict__ Wo,
    unsigned short* __restrict__ wt, unsigned short* __restrict__ wo)
{
    const int which = blockIdx.y;
    const int idx = blockIdx.x * 256 + threadIdx.x;   // 65536 per matrix
    if (which == 3) {
        float4 v = *(const float4*)(Wo + (size_t)idx * 4);
        uint2 o;
        o.x = pack2bf(v.x, v.y);
        o.y = pack2bf(v.z, v.w);
        *(uint2*)(wo + (size_t)idx * 4) = o;
    } else {
        const float* W = (which == 0) ? Wq : (which == 1) ? Wk : Wv;
        const int n   = idx >> 7;          // 0..511  (h*64+d)
        const int dd0 = (idx & 127) * 4;
        const int h = n >> 6, d = n & 63;
        uint2 o;
        o.x = pack2bf(W[((size_t)h * DM + dd0 + 0) * DQ + d],
                      W[((size_t)h * DM + dd0 + 1) * DQ + d]);
        o.y = pack2bf(W[((size_t)h * DM + dd0 + 2) * DQ + d],
                      W[((size_t)h * DM + dd0 + 3) * DQ + d]);
        *(uint2*)(wt + (size_t)which * (DM * DM) + (size_t)n * DM + dd0) = o;
    }
}

// ---------------------------------------------------------------------------
// qkv GEMM: 128x128 tile, BK=64, K=512 (8 k-steps). A (fp32 x, packed to
// bf16 at store) and B (bf16 weights) register-prefetched across the barrier.
// Outputs: which 0 -> q*QSCALE bf16 [b,h,s,d]; 1 -> k bf16 [b,h,s,d];
//          2 -> v bf16 TILE-BLOCKED [b,h][s/64][d][s%64]  (8 KB per 64-kv
//          tile, rows d are 128 B apart -> attn reads it with plain 16B
//          global loads; also improves this store's scatter 4KB->128B).
// grid (64, 4, 3), block 256.
// ---------------------------------------------------------------------------
__global__ __launch_bounds__(256) void qkv_gemm_kernel(
    const float* __restrict__ Xq, const float* __restrict__ Xk,
    const float* __restrict__ Xv, const unsigned short* __restrict__ wt,
    unsigned short* __restrict__ Oq, unsigned short* __restrict__ Ok,
    unsigned short* __restrict__ Ovt)
{
    __shared__ unsigned short As[128][APAD];
    __shared__ unsigned short Bs[128][APAD];

    const int which = blockIdx.z;
    const float* X = (which == 0) ? Xq : (which == 1) ? Xk : Xv;
    const unsigned short* Bt = wt + (size_t)which * (DM * DM);

    const int m0 = blockIdx.x * 128;
    const int n0 = blockIdx.y * 128;
    const int t = threadIdx.x, w = t >> 6, lane = t & 63;
    const int quad = lane >> 4, qr = lane & 15;
    const int arow = t >> 4;           // A staging: 16 rows/pass
    const int acol = (t & 15) * 4;     // float4 col
    const int brow = t >> 3;           // B staging: 32 rows/pass
    const int bcol = (t & 7) * 8;      // ushort8 col
    const int mw = 64 * (w >> 1), nw = 64 * (w & 1);

    floatx4 acc[4][4] = {};
    float4  areg[8];
    ushort8 breg[4];

    #pragma unroll
    for (int i = 0; i < 8; ++i)
        areg[i] = *(const float4*)(X + (size_t)(m0 + i * 16 + arow) * DM + acol);
    #pragma unroll
    for (int i = 0; i < 4; ++i)
        breg[i] = *(const ushort8*)(Bt + (size_t)(n0 + i * 32 + brow) * DM + bcol);

    for (int k0 = 0; k0 < DM; k0 += 64) {
        __syncthreads();
        #pragma unroll
        for (int i = 0; i < 8; ++i) {
            uint2 o;
            o.x = pack2bf(areg[i].x, areg[i].y);
            o.y = pack2bf(areg[i].z, areg[i].w);
            *(uint2*)&As[i * 16 + arow][acol] = o;
        }
        #pragma unroll
        for (int i = 0; i < 4; ++i)
            *(ushort8*)&Bs[i * 32 + brow][bcol] = breg[i];
        __syncthreads();

        if (k0 + 64 < DM) {
            #pragma unroll
            for (int i = 0; i < 8; ++i)
                areg[i] = *(const float4*)(X + (size_t)(m0 + i * 16 + arow) * DM + k0 + 64 + acol);
            #pragma unroll
            for (int i = 0; i < 4; ++i)
                breg[i] = *(const ushort8*)(Bt + (size_t)(n0 + i * 32 + brow) * DM + k0 + 64 + bcol);
        }

        #pragma unroll
        for (int kh = 0; kh < 2; ++kh) {
            short8 af[4], bf[4];
            #pragma unroll
            for (int si = 0; si < 4; ++si)
                af[si] = *(const short8*)&As[mw + 16 * si + qr][kh * 32 + quad * 8];
            #pragma unroll
            for (int sj = 0; sj < 4; ++sj)
                bf[sj] = *(const short8*)&Bs[nw + 16 * sj + qr][kh * 32 + quad * 8];
            #pragma unroll
            for (int si = 0; si < 4; ++si)
                #pragma unroll
                for (int sj = 0; sj < 4; ++sj)
                    acc[si][sj] = __builtin_amdgcn_mfma_f32_16x16x32_bf16(
                        af[si], bf[sj], acc[si][sj], 0, 0, 0);
        }
    }

    const float osc = (which == 0) ? QSCALE : 1.0f;
    if (which < 2) {
        unsigned short* O = (which == 0) ? Oq : Ok;
        #pragma unroll
        for (int si = 0; si < 4; ++si) {
            #pragma unroll
            for (int sj = 0; sj < 4; ++sj) {
                const int col = n0 + nw + 16 * sj + qr;
                const int h = col >> 6, d = col & 63;
                #pragma unroll
                for (int r = 0; r < 4; ++r) {
                    const int row = m0 + mw + 16 * si + quad * 4 + r;
                    const int b = row >> 11, s = row & (SEQ - 1);
                    O[((size_t)(b * NH + h) * SEQ + s) * DQ + d] = f2bf(acc[si][sj][r] * osc);
                }
            }
        }
    } else {
        #pragma unroll
        for (int si = 0; si < 4; ++si) {
            #pragma unroll
            for (int sj = 0; sj < 4; ++sj) {
                const int col = n0 + nw + 16 * sj + qr;
                const int h = col >> 6, d = col & 63;
                #pragma unroll
                for (int r = 0; r < 4; ++r) {
                    const int row = m0 + mw + 16 * si + quad * 4 + r;
                    const int b = row >> 11, s = row & (SEQ - 1);
                    // tile-blocked: [b,h][s>>6][d][s&63]
                    Ovt[(size_t)(b * NH + h) * (DQ * SEQ)
                        + ((size_t)((s >> 6) * 64 + d) << 6) + (s & 63)] = f2bf(acc[si][sj][r]);
                }
            }
        }
    }
}

// ---------------------------------------------------------------------------
// out GEMM: 64x128 tile (512 blocks = 2/CU), BK=64, register-prefetched.
// ---------------------------------------------------------------------------
__global__ __launch_bounds__(256) void out_gemm_kernel(
    const unsigned short* __restrict__ A, const unsigned short* __restrict__ Bt,
    float* __restrict__ C)
{
    __shared__ unsigned short As[64][APAD];
    __shared__ unsigned short Bs[128][APAD];

    const int m0 = blockIdx.x * 64;
    const int n0 = blockIdx.y * 128;
    const int t = threadIdx.x, w = t >> 6, lane = t & 63;
    const int quad = lane >> 4, qr = lane & 15;
    const int brow = t >> 3;           // 32 rows/pass
    const int bcol = (t & 7) * 8;
    const int mw = 32 * (w >> 1), nw = 64 * (w & 1);

    floatx4 acc[2][4] = {};
    ushort8 areg[2], breg[4];

    #pragma unroll
    for (int i = 0; i < 2; ++i)
        areg[i] = *(const ushort8*)(A + (size_t)(m0 + i * 32 + brow) * DM + bcol);
    #pragma unroll
    for (int i = 0; i < 4; ++i)
        breg[i] = *(const ushort8*)(Bt + (size_t)(n0 + i * 32 + brow) * DM + bcol);

    for (int k0 = 0; k0 < DM; k0 += 64) {
        __syncthreads();
        #pragma unroll
        for (int i = 0; i < 2; ++i)
            *(ushort8*)&As[i * 32 + brow][bcol] = areg[i];
        #pragma unroll
        for (int i = 0; i < 4; ++i)
            *(ushort8*)&Bs[i * 32 + brow][bcol] = breg[i];
        __syncthreads();

        if (k0 + 64 < DM) {
            #pragma unroll
            for (int i = 0; i < 2; ++i)
                areg[i] = *(const ushort8*)(A + (size_t)(m0 + i * 32 + brow) * DM + k0 + 64 + bcol);
            #pragma unroll
            for (int i = 0; i < 4; ++i)
                breg[i] = *(const ushort8*)(Bt + (size_t)(n0 + i * 32 + brow) * DM + k0 + 64 + bcol);
        }

        #pragma unroll
        for (int kh = 0; kh < 2; ++kh) {
            short8 af[2], bf[4];
            #pragma unroll
            for (int si = 0; si < 2; ++si)
                af[si] = *(const short8*)&As[mw + 16 * si + qr][kh * 32 + quad * 8];
            #pragma unroll
            for (int sj = 0; sj < 4; ++sj)
                bf[sj] = *(const short8*)&Bs[nw + 16 * sj + qr][kh * 32 + quad * 8];
            #pragma unroll
            for (int si = 0; si < 2; ++si)
                #pragma unroll
                for (int sj = 0; sj < 4; ++sj)
                    acc[si][sj] = __builtin_amdgcn_mfma_f32_16x16x32_bf16(
                        af[si], bf[sj], acc[si][sj], 0, 0, 0);
        }
    }

    #pragma unroll
    for (int si = 0; si < 2; ++si) {
        #pragma unroll
        for (int sj = 0; sj < 4; ++sj) {
            const int col = n0 + nw + 16 * sj + qr;
            #pragma unroll
            for (int r = 0; r < 4; ++r) {
                const int row = m0 + mw + 16 * si + quad * 4 + r;
                C[(size_t)row * DM + col] = acc[si][sj][r];
            }
        }
    }
}

// ---------------------------------------------------------------------------
// flash attention v9: ZERO in-loop LDS / barriers.
// v8 post-mortem: FETCH 12 MB proved K/V is L2-resident (XCD swizzle works),
// yet no pipe >42% busy -> the 2 barriers/iter serialize the 4 waves; LDS
// staging is pure overhead for L2-resident data (guide common-mistake #7).
// v9: every MFMA fragment is a contiguous 16B/lane -> load directly from
// global (L2):
//   ak: K[kt+32kh+ln31][16s+8lh]          (rows 128 B apart)
//   bq: Q[s0+32qh+ln31][16s+8lh]          (loaded once, registers)
//   bv: Vb tile [kt/64][32a+ln31][32kh+16s+8lh]  (tile-blocked ws layout)
// Single-buffered register prefetch: ak(kt+64) issued right after QK
// consumes ak (covered by softmax+PV ~300cy); bv(kt+64) after PV.
// No __shared__ in the loop; 17.4 KB epilogue-only buffer; one barrier
// total. 4 blocks/CU, 16 independent waves/CU; same-CU blocks share the
// same (b,h) K/V stream -> L1 hits. Kept: T1 XCD swizzle, T5 setprio,
// T12 permlane P-exchange, kh-split + epilogue combine.
// grid = (1024), block 256.
// MFMA 32x32x16 layouts: A[m=lane&31][k=(lane>>5)*8+j],
// B[k=(lane>>5)*8+j][n=lane&31], C/D col=lane&31,
// row=(reg&3)+8*(reg>>2)+4*(lane>>5)  (HW-verified m74/m101).
// ---------------------------------------------------------------------------
__global__ __launch_bounds__(256, 4) void attn_kernel(
    const unsigned short* __restrict__ Qp, const unsigned short* __restrict__ Kp,
    const unsigned short* __restrict__ Vbp, unsigned short* __restrict__ Hd)
{
    __shared__ float epi[64 * 66 + 128];   // Obuf 64x66 + lbuf: 17.4 KB

    // XCD-aware decode: xcd = f&7 (round-robin dispatch), each XCD owns
    // 4 complete bh-groups (1024 % 8 == 0 -> bijective).
    const int f    = blockIdx.x;
    const int xcd  = f & 7;
    const int slot = f >> 3;            // 0..127 within XCD
    const int tile = slot & 31;         // q-tile
    const int bhi  = (slot >> 5) * 8 + xcd;   // 0..31
    const int b = bhi >> 3, h = bhi & 7;

    const int s0 = tile * 64;
    const size_t bh    = (size_t)(b * NH + h);
    const size_t base  = bh * SEQ * DQ;       // [b,h,s,d]
    const size_t vbase = bh * DQ * SEQ;       // Vb tiles [s/64][d][64]

    const int t    = threadIdx.x;
    const int w    = t >> 6;
    const int lane = t & 63;
    const int qh   = w >> 1;      // q-half (rows 32qh..32qh+31)
    const int kh   = w & 1;       // kv-half within each 64-kv tile
    const int ln31 = lane & 31;
    const int lh   = lane >> 5;   // lane half

    // ---- Q B-fragments direct from global: B[k=d][n=q], q = s0+32qh+ln31 ----
    short8 bq[4];
    {
        const unsigned short* gq = Qp + base + (size_t)(s0 + 32 * qh + ln31) * DQ + lh * 8;
        #pragma unroll
        for (int s = 0; s < 4; ++s)
            bq[s] = *(const short8*)(gq + 16 * s);
    }

    // per-lane fragment base pointers
    const unsigned short* pK = Kp + base + (size_t)(32 * kh + ln31) * DQ + lh * 8;
    const unsigned short* pV = Vbp + vbase + (size_t)ln31 * 64 + 32 * kh + lh * 8;

    floatx16 accO[2] = {};   // partial O[32q][64dv]: a=dv-block; lane col=dv
    float l_lane = 0.f;

    // ---- prologue: fragment loads for kt=0 ----
    short8 ak[4], bv[4];
    #pragma unroll
    for (int s = 0; s < 4; ++s)
        ak[s] = *(const short8*)(pK + 16 * s);
    #pragma unroll
    for (int a = 0; a < 2; ++a)
        #pragma unroll
        for (int s = 0; s < 2; ++s)
            bv[a * 2 + s] = *(const short8*)(pV + a * 2048 + 16 * s);

    for (int kt = 0; kt < SEQ; kt += 64) {
        // ---- S^T[32kv][32q] = K-half @ Q-half^T (4-chain over d=64) ----
        floatx16 z = {};
        __builtin_amdgcn_s_setprio(1);
        #pragma unroll
        for (int s = 0; s < 4; ++s)
            z = __builtin_amdgcn_mfma_f32_32x32x16_bf16(ak[s], bq[s], z, 0, 0, 0);
        __builtin_amdgcn_s_setprio(0);

        // ---- prefetch next ak (regs free after QK; lands during softmax+PV) ----
        const int ktn = (kt + 64 < SEQ) ? kt + 64 : kt;
        {
            const unsigned short* nK = pK + (size_t)ktn * DQ;
            #pragma unroll
            for (int s = 0; s < 4; ++s)
                ak[s] = *(const short8*)(nK + 16 * s);
        }

        // ---- exp2, l accumulate, pack P (reg 4g+j -> kv = 8g+4lh+j) ----
        unsigned wg[4][2];
        #pragma unroll
        for (int g = 0; g < 4; ++g) {
            const float p0 = __builtin_amdgcn_exp2f(z[4 * g + 0]);
            const float p1 = __builtin_amdgcn_exp2f(z[4 * g + 1]);
            const float p2 = __builtin_amdgcn_exp2f(z[4 * g + 2]);
            const float p3 = __builtin_amdgcn_exp2f(z[4 * g + 3]);
            l_lane += (p0 + p1) + (p2 + p3);
            wg[g][0] = pack2bf(p0, p1);
            wg[g][1] = pack2bf(p2, p3);
        }

        // ---- T12: build PV A-fragments in-register via permlane32_swap ----
        const uintx2 e0 = __builtin_amdgcn_permlane32_swap(wg[0][0], wg[1][0], false, false);
        const uintx2 e1 = __builtin_amdgcn_permlane32_swap(wg[0][1], wg[1][1], false, false);
        const uintx2 e2 = __builtin_amdgcn_permlane32_swap(wg[2][0], wg[3][0], false, false);
        const uintx2 e3 = __builtin_amdgcn_permlane32_swap(wg[2][1], wg[3][1], false, false);
        uintx4 ua0, ua1;
        ua0[0] = e0[0]; ua0[1] = e1[0]; ua0[2] = e0[1]; ua0[3] = e1[1];
        ua1[0] = e2[0]; ua1[1] = e3[0]; ua1[2] = e2[1]; ua1[3] = e3[1];
        const short8 ap0 = __builtin_bit_cast(short8, ua0);
        const short8 ap1 = __builtin_bit_cast(short8, ua1);

        // ---- PV: accO[a] += P[32q][32kv] @ V[32kv][32dv] ----
        __builtin_amdgcn_s_setprio(1);
        #pragma unroll
        for (int a = 0; a < 2; ++a) {
            accO[a] = __builtin_amdgcn_mfma_f32_32x32x16_bf16(ap0, bv[a * 2 + 0], accO[a], 0, 0, 0);
            accO[a] = __builtin_amdgcn_mfma_f32_32x32x16_bf16(ap1, bv[a * 2 + 1], accO[a], 0, 0, 0);
        }
        __builtin_amdgcn_s_setprio(0);

        // ---- prefetch next bv (regs free after PV; lands by next PV) ----
        {
            const unsigned short* nV = pV + (size_t)(ktn >> 6) * 4096;
            #pragma unroll
            for (int a = 0; a < 2; ++a)
                #pragma unroll
                for (int s = 0; s < 2; ++s)
                    bv[a * 2 + s] = *(const short8*)(nV + a * 2048 + 16 * s);
        }
    }

    // ---- cross-kh combine: O and l, via epilogue-only LDS ----
    float l2 = l_lane + __shfl_xor(l_lane, 32);   // full kv-half sum for q=32qh+ln31
    float* Obuf = epi;                 // 64x66 f32
    float* lbuf = epi + 64 * 66;       // [0..63] kh0-l, [64..127] inv_l

    if (kh == 0) {
        if (lane < 32) lbuf[qh * 32 + lane] = l2;
        #pragma unroll
        for (int a = 0; a < 2; ++a)
            #pragma unroll
            for (int r = 0; r < 16; ++r) {
                const int qrow = (r & 3) + 8 * (r >> 2) + 4 * lh;
                Obuf[(32 * qh + qrow) * 66 + 32 * a + ln31] = accO[a][r];
            }
    }
    __syncthreads();

    if (kh == 1) {
        const float ltot = l2 + lbuf[qh * 32 + ln31];
        if (lane < 32) lbuf[64 + qh * 32 + lane] = 1.0f / ltot;  // same-wave RAW
        #pragma unroll
        for (int a = 0; a < 2; ++a)
            #pragma unroll
            for (int r = 0; r < 16; ++r) {
                const int qrow = (r & 3) + 8 * (r >> 2) + 4 * lh;
                const float o = accO[a][r] + Obuf[(32 * qh + qrow) * 66 + 32 * a + ln31];
                const float iv = lbuf[64 + qh * 32 + qrow];
                Hd[base + (size_t)(s0 + 32 * qh + qrow) * DQ + 32 * a + ln31] = f2bf(o * iv);
            }
    }
}

// ---------------------------------------------------------------------------
// kernel_launch
// Workspace (ushort units):
//   wt:    0        (3 x 262144)    qkv weights bf16, B^T [h*64+d][dd]
//   wo:    786432   (262144)        Wout bf16 [o][c]
//   q_ws:  1048576  (4194304)       q*QSCALE bf16 [b,h,s,d]
//   k_ws:  5242880  (4194304)       k bf16 [b,h,s,d]
//   vt_ws: 9437184  (4194304)       v bf16 tile-blocked [b,h][s/64][d][s%64]
//   h_ws:  13631488 (4194304)       heads bf16 (flat GEMM-A view)
// total ~34 MB
// ---------------------------------------------------------------------------
extern "C" void kernel_launch(void* const* d_in, const int* in_sizes, int n_in,
                              void* d_out, int out_size, void* d_ws, size_t ws_size,
                              hipStream_t stream) {
    const float* xq = (const float*)d_in[0];
    const float* xk = (const float*)d_in[1];
    const float* xv = (const float*)d_in[2];
    const float* Qw = (const float*)d_in[3];
    const float* Kw = (const float*)d_in[4];
    const float* Vw = (const float*)d_in[5];
    const float* Wo = (const float*)d_in[6];
    float* out = (float*)d_out;

    unsigned short* ws = (unsigned short*)d_ws;
    unsigned short* wt    = ws;
    unsigned short* wo    = ws + (size_t)786432;
    unsigned short* q_ws  = ws + (size_t)1048576;
    unsigned short* k_ws  = ws + (size_t)5242880;
    unsigned short* vt_ws = ws + (size_t)9437184;
    unsigned short* h_ws  = ws + (size_t)13631488;

    convert_w_kernel<<<dim3(256, 4), 256, 0, stream>>>(Qw, Kw, Vw, Wo, wt, wo);
    qkv_gemm_kernel<<<dim3(64, 4, 3), 256, 0, stream>>>(xq, xk, xv, wt, q_ws, k_ws, vt_ws);
    attn_kernel<<<dim3(1024), 256, 0, stream>>>(q_ws, k_ws, vt_ws, h_ws);
    out_gemm_kernel<<<dim3(128, 4), 256, 0, stream>>>(h_ws, wo, out);
}

// Round 4
// 187.111 us; speedup vs baseline: 1.3629x; 1.3629x over previous
//
#include <hip/hip_runtime.h>
#include <math.h>

// Problem constants (B=4, S=2048, D_MODEL=512, H=8, DQ=64)
#define BATCH 4
#define SEQ   2048
#define DM    512
#define NH    8
#define DQ    64
#define BS    (BATCH*SEQ)     // 8192 rows
#define APAD  72              // padded tile stride in gemms

// q pre-scale: 1/sqrt(64) * log2(e), so softmax uses native 2^x (v_exp_f32)
#define QSCALE 0.18033688011112042f

typedef short  short8   __attribute__((ext_vector_type(8)));
typedef float  floatx4  __attribute__((ext_vector_type(4)));
typedef float  floatx16 __attribute__((ext_vector_type(16)));
typedef unsigned short ushort8 __attribute__((ext_vector_type(8)));
typedef unsigned uintx2 __attribute__((ext_vector_type(2)));
typedef unsigned uintx4 __attribute__((ext_vector_type(4)));

// cheap bf16: round-half-up (1 add + shift). Ties-only delta vs RNE.
__device__ __forceinline__ unsigned short f2bf(float f) {
    return (unsigned short)((__float_as_uint(f) + 0x8000u) >> 16);
}
// pack two floats -> two bf16 in one u32 (lo = a, hi = b): 2 adds + 1 v_perm
__device__ __forceinline__ unsigned pack2bf(float a, float b) {
    unsigned ua = __float_as_uint(a) + 0x8000u;
    unsigned ub = __float_as_uint(b) + 0x8000u;
    return __builtin_amdgcn_perm(ub, ua, 0x07060302u);  // {ub[3],ub[2],ua[3],ua[2]}
}

// ---------------------------------------------------------------------------
// convert_w: pack weights to bf16 B^T layout [n][k].
//   which 0..2: wt[which][h*64+d][dd] = W[h][dd][d]  (qkv projections)
//   which 3:    wo[o][c] = Wout[o][c]                 (already B^T)
// grid (256, 4).
// ---------------------------------------------------------------------------
__global__ __launch_bounds__(256) void convert_w_kernel(
    const float* __restrict__ Wq, const float* __restrict__ Wk,
    const float* __restrict__ Wv, const float* __restrict__ Wo,
    unsigned short* __restrict__ wt, unsigned short* __restrict__ wo)
{
    const int which = blockIdx.y;
    const int idx = blockIdx.x * 256 + threadIdx.x;   // 65536 per matrix
    if (which == 3) {
        float4 v = *(const float4*)(Wo + (size_t)idx * 4);
        uint2 o;
        o.x = pack2bf(v.x, v.y);
        o.y = pack2bf(v.z, v.w);
        *(uint2*)(wo + (size_t)idx * 4) = o;
    } else {
        const float* W = (which == 0) ? Wq : (which == 1) ? Wk : Wv;
        const int n   = idx >> 7;          // 0..511  (h*64+d)
        const int dd0 = (idx & 127) * 4;
        const int h = n >> 6, d = n & 63;
        uint2 o;
        o.x = pack2bf(W[((size_t)h * DM + dd0 + 0) * DQ + d],
                      W[((size_t)h * DM + dd0 + 1) * DQ + d]);
        o.y = pack2bf(W[((size_t)h * DM + dd0 + 2) * DQ + d],
                      W[((size_t)h * DM + dd0 + 3) * DQ + d]);
        *(uint2*)(wt + (size_t)which * (DM * DM) + (size_t)n * DM + dd0) = o;
    }
}

// ---------------------------------------------------------------------------
// qkv GEMM: 128x128 tile, BK=64, K=512 (8 k-steps). A (fp32 x, packed to
// bf16 at store) and B (bf16 weights) register-prefetched across the barrier.
// Outputs: which 0 -> q*QSCALE bf16 [b,h,s,d]; 1 -> k bf16 [b,h,s,d];
//          2 -> v bf16 TILE-BLOCKED [b,h][s/64][d][s%64]  (8 KB per 64-kv
//          tile; 128 B store scatter here, coalesced staging reads in attn).
// grid (64, 4, 3), block 256.
// ---------------------------------------------------------------------------
__global__ __launch_bounds__(256) void qkv_gemm_kernel(
    const float* __restrict__ Xq, const float* __restrict__ Xk,
    const float* __restrict__ Xv, const unsigned short* __restrict__ wt,
    unsigned short* __restrict__ Oq, unsigned short* __restrict__ Ok,
    unsigned short* __restrict__ Ovt)
{
    __shared__ unsigned short As[128][APAD];
    __shared__ unsigned short Bs[128][APAD];

    const int which = blockIdx.z;
    const float* X = (which == 0) ? Xq : (which == 1) ? Xk : Xv;
    const unsigned short* Bt = wt + (size_t)which * (DM * DM);

    const int m0 = blockIdx.x * 128;
    const int n0 = blockIdx.y * 128;
    const int t = threadIdx.x, w = t >> 6, lane = t & 63;
    const int quad = lane >> 4, qr = lane & 15;
    const int arow = t >> 4;           // A staging: 16 rows/pass
    const int acol = (t & 15) * 4;     // float4 col
    const int brow = t >> 3;           // B staging: 32 rows/pass
    const int bcol = (t & 7) * 8;      // ushort8 col
    const int mw = 64 * (w >> 1), nw = 64 * (w & 1);

    floatx4 acc[4][4] = {};
    float4  areg[8];
    ushort8 breg[4];

    #pragma unroll
    for (int i = 0; i < 8; ++i)
        areg[i] = *(const float4*)(X + (size_t)(m0 + i * 16 + arow) * DM + acol);
    #pragma unroll
    for (int i = 0; i < 4; ++i)
        breg[i] = *(const ushort8*)(Bt + (size_t)(n0 + i * 32 + brow) * DM + bcol);

    for (int k0 = 0; k0 < DM; k0 += 64) {
        __syncthreads();
        #pragma unroll
        for (int i = 0; i < 8; ++i) {
            uint2 o;
            o.x = pack2bf(areg[i].x, areg[i].y);
            o.y = pack2bf(areg[i].z, areg[i].w);
            *(uint2*)&As[i * 16 + arow][acol] = o;
        }
        #pragma unroll
        for (int i = 0; i < 4; ++i)
            *(ushort8*)&Bs[i * 32 + brow][bcol] = breg[i];
        __syncthreads();

        if (k0 + 64 < DM) {
            #pragma unroll
            for (int i = 0; i < 8; ++i)
                areg[i] = *(const float4*)(X + (size_t)(m0 + i * 16 + arow) * DM + k0 + 64 + acol);
            #pragma unroll
            for (int i = 0; i < 4; ++i)
                breg[i] = *(const ushort8*)(Bt + (size_t)(n0 + i * 32 + brow) * DM + k0 + 64 + bcol);
        }

        #pragma unroll
        for (int kh = 0; kh < 2; ++kh) {
            short8 af[4], bf[4];
            #pragma unroll
            for (int si = 0; si < 4; ++si)
                af[si] = *(const short8*)&As[mw + 16 * si + qr][kh * 32 + quad * 8];
            #pragma unroll
            for (int sj = 0; sj < 4; ++sj)
                bf[sj] = *(const short8*)&Bs[nw + 16 * sj + qr][kh * 32 + quad * 8];
            #pragma unroll
            for (int si = 0; si < 4; ++si)
                #pragma unroll
                for (int sj = 0; sj < 4; ++sj)
                    acc[si][sj] = __builtin_amdgcn_mfma_f32_16x16x32_bf16(
                        af[si], bf[sj], acc[si][sj], 0, 0, 0);
        }
    }

    const float osc = (which == 0) ? QSCALE : 1.0f;
    if (which < 2) {
        unsigned short* O = (which == 0) ? Oq : Ok;
        #pragma unroll
        for (int si = 0; si < 4; ++si) {
            #pragma unroll
            for (int sj = 0; sj < 4; ++sj) {
                const int col = n0 + nw + 16 * sj + qr;
                const int h = col >> 6, d = col & 63;
                #pragma unroll
                for (int r = 0; r < 4; ++r) {
                    const int row = m0 + mw + 16 * si + quad * 4 + r;
                    const int b = row >> 11, s = row & (SEQ - 1);
                    O[((size_t)(b * NH + h) * SEQ + s) * DQ + d] = f2bf(acc[si][sj][r] * osc);
                }
            }
        }
    } else {
        #pragma unroll
        for (int si = 0; si < 4; ++si) {
            #pragma unroll
            for (int sj = 0; sj < 4; ++sj) {
                const int col = n0 + nw + 16 * sj + qr;
                const int h = col >> 6, d = col & 63;
                #pragma unroll
                for (int r = 0; r < 4; ++r) {
                    const int row = m0 + mw + 16 * si + quad * 4 + r;
                    const int b = row >> 11, s = row & (SEQ - 1);
                    // tile-blocked: [b,h][s>>6][d][s&63]
                    Ovt[(size_t)(b * NH + h) * (DQ * SEQ)
                        + ((size_t)((s >> 6) * 64 + d) << 6) + (s & 63)] = f2bf(acc[si][sj][r]);
                }
            }
        }
    }
}

// ---------------------------------------------------------------------------
// out GEMM: 64x128 tile (512 blocks = 2/CU), BK=64, register-prefetched.
// ---------------------------------------------------------------------------
__global__ __launch_bounds__(256) void out_gemm_kernel(
    const unsigned short* __restrict__ A, const unsigned short* __restrict__ Bt,
    float* __restrict__ C)
{
    __shared__ unsigned short As[64][APAD];
    __shared__ unsigned short Bs[128][APAD];

    const int m0 = blockIdx.x * 64;
    const int n0 = blockIdx.y * 128;
    const int t = threadIdx.x, w = t >> 6, lane = t & 63;
    const int quad = lane >> 4, qr = lane & 15;
    const int brow = t >> 3;           // 32 rows/pass
    const int bcol = (t & 7) * 8;
    const int mw = 32 * (w >> 1), nw = 64 * (w & 1);

    floatx4 acc[2][4] = {};
    ushort8 areg[2], breg[4];

    #pragma unroll
    for (int i = 0; i < 2; ++i)
        areg[i] = *(const ushort8*)(A + (size_t)(m0 + i * 32 + brow) * DM + bcol);
    #pragma unroll
    for (int i = 0; i < 4; ++i)
        breg[i] = *(const ushort8*)(Bt + (size_t)(n0 + i * 32 + brow) * DM + bcol);

    for (int k0 = 0; k0 < DM; k0 += 64) {
        __syncthreads();
        #pragma unroll
        for (int i = 0; i < 2; ++i)
            *(ushort8*)&As[i * 32 + brow][bcol] = areg[i];
        #pragma unroll
        for (int i = 0; i < 4; ++i)
            *(ushort8*)&Bs[i * 32 + brow][bcol] = breg[i];
        __syncthreads();

        if (k0 + 64 < DM) {
            #pragma unroll
            for (int i = 0; i < 2; ++i)
                areg[i] = *(const ushort8*)(A + (size_t)(m0 + i * 32 + brow) * DM + k0 + 64 + bcol);
            #pragma unroll
            for (int i = 0; i < 4; ++i)
                breg[i] = *(const ushort8*)(Bt + (size_t)(n0 + i * 32 + brow) * DM + k0 + 64 + bcol);
        }

        #pragma unroll
        for (int kh = 0; kh < 2; ++kh) {
            short8 af[2], bf[4];
            #pragma unroll
            for (int si = 0; si < 2; ++si)
                af[si] = *(const short8*)&As[mw + 16 * si + qr][kh * 32 + quad * 8];
            #pragma unroll
            for (int sj = 0; sj < 4; ++sj)
                bf[sj] = *(const short8*)&Bs[nw + 16 * sj + qr][kh * 32 + quad * 8];
            #pragma unroll
            for (int si = 0; si < 2; ++si)
                #pragma unroll
                for (int sj = 0; sj < 4; ++sj)
                    acc[si][sj] = __builtin_amdgcn_mfma_f32_16x16x32_bf16(
                        af[si], bf[sj], acc[si][sj], 0, 0, 0);
        }
    }

    #pragma unroll
    for (int si = 0; si < 2; ++si) {
        #pragma unroll
        for (int sj = 0; sj < 4; ++sj) {
            const int col = n0 + nw + 16 * sj + qr;
            #pragma unroll
            for (int r = 0; r < 4; ++r) {
                const int row = m0 + mw + 16 * si + quad * 4 + r;
                C[(size_t)row * DM + col] = acc[si][sj][r];
            }
        }
    }
}

// ---------------------------------------------------------------------------
// flash attention v10: v8's staged-LDS compute loop + double-buffered K/V
// (ONE barrier/iter) + 5 blocks/CU.
// v9 post-mortem: fragment-direct global loads (16B/lane at 128B stride)
// touch 32 cache lines per wave-load vs 4 for coalesced staging -> L1
// transaction-bound, 130 us. LDS staging IS the coalescing transpose.
// v10 structure per iter: write regs(t+1)->buf[cur^1], issue coalesced
// loads(t+2)->regs, compute QK/softmax/PV from buf[cur], ONE syncthreads.
// Write/read never share a buffer; v8's first barrier deleted; loads get a
// full compute phase of latency cover (T14 depth-2).
// Qs dropped (bq loaded once direct from global); LDS = 2x16KB = 32 KB ->
// 5 blocks/CU (was 4). Kept: XOR swizzle, T1 XCD decode, T5 setprio, T12
// permlane P-exchange, kh-split + epilogue combine (aliased over K/V bufs).
// K staged coalesced from [b,h,s,d]; V staged coalesced from tile-blocked
// [b,h][kt/64][d][64]. grid = (1024), block 256.
// MFMA 32x32x16 layouts: A[m=lane&31][k=(lane>>5)*8+j],
// B[k=(lane>>5)*8+j][n=lane&31], C/D col=lane&31,
// row=(reg&3)+8*(reg>>2)+4*(lane>>5)  (HW-verified m74/m101).
// ---------------------------------------------------------------------------
__global__ __launch_bounds__(256, 4) void attn_kernel(
    const unsigned short* __restrict__ Qp, const unsigned short* __restrict__ Kp,
    const unsigned short* __restrict__ Vbp, unsigned short* __restrict__ Hd)
{
    __shared__ unsigned short smem[2 * 8192];   // 32 KB: buf b = {Ks 4096, Vts 4096}

    // XCD-aware decode: xcd = f&7 (round-robin dispatch), each XCD owns
    // 4 complete bh-groups (1024 % 8 == 0 -> bijective).
    const int f    = blockIdx.x;
    const int xcd  = f & 7;
    const int slot = f >> 3;            // 0..127 within XCD
    const int tile = slot & 31;         // q-tile
    const int bhi  = (slot >> 5) * 8 + xcd;   // 0..31
    const int b = bhi >> 3, h = bhi & 7;

    const int s0 = tile * 64;
    const size_t bh    = (size_t)(b * NH + h);
    const size_t base  = bh * SEQ * DQ;       // [b,h,s,d]
    const size_t vbase = bh * DQ * SEQ;       // Vb tiles [s/64][d][64]

    const int t    = threadIdx.x;
    const int w    = t >> 6;
    const int lane = t & 63;
    const int qh   = w >> 1;      // q-half (rows 32qh..32qh+31)
    const int kh   = w & 1;       // kv-half within each 64-kv tile
    const int ln31 = lane & 31;
    const int lh   = lane >> 5;   // lane half

    // ---- Q B-fragments direct from global (once): B[k=d][n=q] ----
    short8 bq[4];
    {
        const unsigned short* gq = Qp + base + (size_t)(s0 + 32 * qh + ln31) * DQ + lh * 8;
        #pragma unroll
        for (int s = 0; s < 4; ++s)
            bq[s] = *(const short8*)(gq + 16 * s);
    }

    // staging geometry: 32 rows/pass, ushort8 cols, XOR swizzle
    const int srow = t >> 3;            // 0..31
    const int scol = (t & 7) * 8;
    const int ssc  = scol ^ ((srow & 7) * 8);   // (srow+32 has same row&7)
    const unsigned short* gK = Kp + base;
    const unsigned short* gV = Vbp + vbase;

    // ---- prologue: tile 0 regs -> buf0; tile 1 -> regs ----
    ushort8 kreg[2], vreg[2];
    #pragma unroll
    for (int i = 0; i < 2; ++i) {
        const int row = srow + 32 * i;
        kreg[i] = *(const ushort8*)(gK + (size_t)row * DQ + scol);
        vreg[i] = *(const ushort8*)(gV + row * 64 + scol);
    }
    #pragma unroll
    for (int i = 0; i < 2; ++i) {
        const int row = srow + 32 * i;
        *(ushort8*)&smem[row * 64 + ssc]        = kreg[i];
        *(ushort8*)&smem[4096 + row * 64 + ssc] = vreg[i];
    }
    #pragma unroll
    for (int i = 0; i < 2; ++i) {
        const int row = srow + 32 * i;
        kreg[i] = *(const ushort8*)(gK + (size_t)(64 + row) * DQ + scol);
        vreg[i] = *(const ushort8*)(gV + 4096 + row * 64 + scol);
    }
    __syncthreads();

    floatx16 accO[2] = {};   // partial O[32q][64dv]: a=dv-block; lane col=dv
    float l_lane = 0.f;

    int cur = 0;
    for (int kt = 0; kt < SEQ; kt += 64, cur ^= 1) {
        const unsigned short* Ks  = smem + cur * 8192;
        const unsigned short* Vts = Ks + 4096;

        // ---- write next tile to the other buffer, then issue t+2 loads ----
        if (kt + 64 < SEQ) {
            unsigned short* Kn = smem + (cur ^ 1) * 8192;
            #pragma unroll
            for (int i = 0; i < 2; ++i) {
                const int row = srow + 32 * i;
                *(ushort8*)&Kn[row * 64 + ssc]        = kreg[i];
                *(ushort8*)&Kn[4096 + row * 64 + ssc] = vreg[i];
            }
            if (kt + 128 < SEQ) {
                #pragma unroll
                for (int i = 0; i < 2; ++i) {
                    const int row = srow + 32 * i;
                    kreg[i] = *(const ushort8*)(gK + (size_t)(kt + 128 + row) * DQ + scol);
                    vreg[i] = *(const ushort8*)(gV + ((kt + 128) >> 6) * 4096 + row * 64 + scol);
                }
            }
        }

        // ---- S^T[32kv][32q] = K-half @ Q-half^T (4-chain over d=64) ----
        floatx16 z = {};
        __builtin_amdgcn_s_setprio(1);
        {
            const int krow = 32 * kh + ln31;
            #pragma unroll
            for (int s = 0; s < 4; ++s) {
                const short8 ak = *(const short8*)&Ks[krow * 64 + ((16 * s + lh * 8) ^ ((krow & 7) * 8))];
                z = __builtin_amdgcn_mfma_f32_32x32x16_bf16(ak, bq[s], z, 0, 0, 0);
            }
        }
        __builtin_amdgcn_s_setprio(0);

        // ---- exp2, l accumulate, pack P (reg 4g+j -> kv = 8g+4lh+j) ----
        unsigned wg[4][2];
        #pragma unroll
        for (int g = 0; g < 4; ++g) {
            const float p0 = __builtin_amdgcn_exp2f(z[4 * g + 0]);
            const float p1 = __builtin_amdgcn_exp2f(z[4 * g + 1]);
            const float p2 = __builtin_amdgcn_exp2f(z[4 * g + 2]);
            const float p3 = __builtin_amdgcn_exp2f(z[4 * g + 3]);
            l_lane += (p0 + p1) + (p2 + p3);
            wg[g][0] = pack2bf(p0, p1);
            wg[g][1] = pack2bf(p2, p3);
        }

        // ---- T12: build PV A-fragments in-register via permlane32_swap ----
        const uintx2 e0 = __builtin_amdgcn_permlane32_swap(wg[0][0], wg[1][0], false, false);
        const uintx2 e1 = __builtin_amdgcn_permlane32_swap(wg[0][1], wg[1][1], false, false);
        const uintx2 e2 = __builtin_amdgcn_permlane32_swap(wg[2][0], wg[3][0], false, false);
        const uintx2 e3 = __builtin_amdgcn_permlane32_swap(wg[2][1], wg[3][1], false, false);
        uintx4 ua0, ua1;
        ua0[0] = e0[0]; ua0[1] = e1[0]; ua0[2] = e0[1]; ua0[3] = e1[1];
        ua1[0] = e2[0]; ua1[1] = e3[0]; ua1[2] = e2[1]; ua1[3] = e3[1];
        const short8 ap0 = __builtin_bit_cast(short8, ua0);
        const short8 ap1 = __builtin_bit_cast(short8, ua1);

        // ---- PV: accO[a] += P[32q][32kv] @ V[32kv][32dv] ----
        __builtin_amdgcn_s_setprio(1);
        #pragma unroll
        for (int a = 0; a < 2; ++a) {
            const int vrow = 32 * a + ln31;
            const short8 bv0 = *(const short8*)&Vts[vrow * 64 + ((32 * kh + lh * 8) ^ ((vrow & 7) * 8))];
            const short8 bv1 = *(const short8*)&Vts[vrow * 64 + ((32 * kh + 16 + lh * 8) ^ ((vrow & 7) * 8))];
            accO[a] = __builtin_amdgcn_mfma_f32_32x32x16_bf16(ap0, bv0, accO[a], 0, 0, 0);
            accO[a] = __builtin_amdgcn_mfma_f32_32x32x16_bf16(ap1, bv1, accO[a], 0, 0, 0);
        }
        __builtin_amdgcn_s_setprio(0);

        __syncthreads();   // buf[cur^1] writes visible; buf[cur] reads done
    }

    // ---- cross-kh combine: O and l, via LDS aliased over dead K/V bufs ----
    float l2 = l_lane + __shfl_xor(l_lane, 32);   // full kv-half sum for q=32qh+ln31
    float* Obuf = (float*)smem;                   // 64x66 f32 = 16.9 KB
    float* lbuf = (float*)smem + 8064;            // floats 8064..8191 (tail 512 B)

    if (kh == 0) {
        if (lane < 32) lbuf[qh * 32 + lane] = l2;
        #pragma unroll
        for (int a = 0; a < 2; ++a)
            #pragma unroll
            for (int r = 0; r < 16; ++r) {
                const int qrow = (r & 3) + 8 * (r >> 2) + 4 * lh;
                Obuf[(32 * qh + qrow) * 66 + 32 * a + ln31] = accO[a][r];
            }
    }
    __syncthreads();

    if (kh == 1) {
        const float ltot = l2 + lbuf[qh * 32 + ln31];
        if (lane < 32) lbuf[64 + qh * 32 + lane] = 1.0f / ltot;  // same-wave RAW
        #pragma unroll
        for (int a = 0; a < 2; ++a)
            #pragma unroll
            for (int r = 0; r < 16; ++r) {
                const int qrow = (r & 3) + 8 * (r >> 2) + 4 * lh;
                const float o = accO[a][r] + Obuf[(32 * qh + qrow) * 66 + 32 * a + ln31];
                const float iv = lbuf[64 + qh * 32 + qrow];
                Hd[base + (size_t)(s0 + 32 * qh + qrow) * DQ + 32 * a + ln31] = f2bf(o * iv);
            }
    }
}

// ---------------------------------------------------------------------------
// kernel_launch
// Workspace (ushort units):
//   wt:    0        (3 x 262144)    qkv weights bf16, B^T [h*64+d][dd]
//   wo:    786432   (262144)        Wout bf16 [o][c]
//   q_ws:  1048576  (4194304)       q*QSCALE bf16 [b,h,s,d]
//   k_ws:  5242880  (4194304)       k bf16 [b,h,s,d]
//   vt_ws: 9437184  (4194304)       v bf16 tile-blocked [b,h][s/64][d][s%64]
//   h_ws:  13631488 (4194304)       heads bf16 (flat GEMM-A view)
// total ~34 MB
// ---------------------------------------------------------------------------
extern "C" void kernel_launch(void* const* d_in, const int* in_sizes, int n_in,
                              void* d_out, int out_size, void* d_ws, size_t ws_size,
                              hipStream_t stream) {
    const float* xq = (const float*)d_in[0];
    const float* xk = (const float*)d_in[1];
    const float* xv = (const float*)d_in[2];
    const float* Qw = (const float*)d_in[3];
    const float* Kw = (const float*)d_in[4];
    const float* Vw = (const float*)d_in[5];
    const float* Wo = (const float*)d_in[6];
    float* out = (float*)d_out;

    unsigned short* ws = (unsigned short*)d_ws;
    unsigned short* wt    = ws;
    unsigned short* wo    = ws + (size_t)786432;
    unsigned short* q_ws  = ws + (size_t)1048576;
    unsigned short* k_ws  = ws + (size_t)5242880;
    unsigned short* vt_ws = ws + (size_t)9437184;
    unsigned short* h_ws  = ws + (size_t)13631488;

    convert_w_kernel<<<dim3(256, 4), 256, 0, stream>>>(Qw, Kw, Vw, Wo, wt, wo);
    qkv_gemm_kernel<<<dim3(64, 4, 3), 256, 0, stream>>>(xq, xk, xv, wt, q_ws, k_ws, vt_ws);
    attn_kernel<<<dim3(1024), 256, 0, stream>>>(q_ws, k_ws, vt_ws, h_ws);
    out_gemm_kernel<<<dim3(128, 4), 256, 0, stream>>>(h_ws, wo, out);
}

// Round 5
// 181.425 us; speedup vs baseline: 1.4056x; 1.0313x over previous
//
#include <hip/hip_runtime.h>
#include <math.h>

// Problem constants (B=4, S=2048, D_MODEL=512, H=8, DQ=64)
#define BATCH 4
#define SEQ   2048
#define DM    512
#define NH    8
#define DQ    64
#define BS    (BATCH*SEQ)     // 8192 rows
#define APAD  72              // padded tile stride in gemms

// q pre-scale: 1/sqrt(64) * log2(e), so softmax uses native 2^x (v_exp_f32)
#define QSCALE 0.18033688011112042f

typedef short  short8   __attribute__((ext_vector_type(8)));
typedef float  floatx4  __attribute__((ext_vector_type(4)));
typedef float  floatx16 __attribute__((ext_vector_type(16)));
typedef unsigned short ushort8 __attribute__((ext_vector_type(8)));
typedef unsigned uintx2 __attribute__((ext_vector_type(2)));
typedef unsigned uintx4 __attribute__((ext_vector_type(4)));

// cheap bf16: round-half-up (1 add + shift). Ties-only delta vs RNE.
__device__ __forceinline__ unsigned short f2bf(float f) {
    return (unsigned short)((__float_as_uint(f) + 0x8000u) >> 16);
}
// pack two floats -> two bf16 in one u32 (lo = a, hi = b): 2 adds + 1 v_perm
__device__ __forceinline__ unsigned pack2bf(float a, float b) {
    unsigned ua = __float_as_uint(a) + 0x8000u;
    unsigned ub = __float_as_uint(b) + 0x8000u;
    return __builtin_amdgcn_perm(ub, ua, 0x07060302u);  // {ub[3],ub[2],ua[3],ua[2]}
}

// ---------------------------------------------------------------------------
// convert_w: pack weights to bf16 B^T layout [n][k].
//   which 0..2: wt[which][h*64+d][dd] = W[h][dd][d]  (qkv projections)
//   which 3:    wo[o][c] = Wout[o][c]                 (already B^T)
// grid (256, 4).
// ---------------------------------------------------------------------------
__global__ __launch_bounds__(256) void convert_w_kernel(
    const float* __restrict__ Wq, const float* __restrict__ Wk,
    const float* __restrict__ Wv, const float* __restrict__ Wo,
    unsigned short* __restrict__ wt, unsigned short* __restrict__ wo)
{
    const int which = blockIdx.y;
    const int idx = blockIdx.x * 256 + threadIdx.x;   // 65536 per matrix
    if (which == 3) {
        float4 v = *(const float4*)(Wo + (size_t)idx * 4);
        uint2 o;
        o.x = pack2bf(v.x, v.y);
        o.y = pack2bf(v.z, v.w);
        *(uint2*)(wo + (size_t)idx * 4) = o;
    } else {
        const float* W = (which == 0) ? Wq : (which == 1) ? Wk : Wv;
        const int n   = idx >> 7;          // 0..511  (h*64+d)
        const int dd0 = (idx & 127) * 4;
        const int h = n >> 6, d = n & 63;
        uint2 o;
        o.x = pack2bf(W[((size_t)h * DM + dd0 + 0) * DQ + d],
                      W[((size_t)h * DM + dd0 + 1) * DQ + d]);
        o.y = pack2bf(W[((size_t)h * DM + dd0 + 2) * DQ + d],
                      W[((size_t)h * DM + dd0 + 3) * DQ + d]);
        *(uint2*)(wt + (size_t)which * (DM * DM) + (size_t)n * DM + dd0) = o;
    }
}

// ---------------------------------------------------------------------------
// qkv GEMM: 128x128 tile, BK=64, K=512 (8 k-steps). A (fp32 x, packed to
// bf16 at store) and B (bf16 weights) register-prefetched across the barrier.
// Outputs:
//   which 0 -> q*QSCALE bf16 [b,h,s,d]                (attn reads once, direct)
//   which 1 -> k bf16 FRAGMENT-MAJOR Kf:
//       [bh][s>>5][d>>4][lane=((d>>3)&1)*32+(s&31)][d&7]
//       (each 32-kv x 16-d MFMA A-fragment = contiguous [lane][16B] 1KB chunk;
//        attn loads it as base + lane*16, 4 cache lines per wave-load)
//   which 2 -> v bf16 FRAGMENT-MAJOR Vf:
//       [bh][s>>6][(s>>5)&1][d>>5][(s>>4)&1][lane=((s>>3)&1)*32+(d&31)][s&7]
//       (B-fragments of V^T for PV, same lane-contiguous property)
// grid (64, 4, 3), block 256.
// ---------------------------------------------------------------------------
__global__ __launch_bounds__(256) void qkv_gemm_kernel(
    const float* __restrict__ Xq, const float* __restrict__ Xk,
    const float* __restrict__ Xv, const unsigned short* __restrict__ wt,
    unsigned short* __restrict__ Oq, unsigned short* __restrict__ Ok,
    unsigned short* __restrict__ Ovt)
{
    __shared__ unsigned short As[128][APAD];
    __shared__ unsigned short Bs[128][APAD];

    const int which = blockIdx.z;
    const float* X = (which == 0) ? Xq : (which == 1) ? Xk : Xv;
    const unsigned short* Bt = wt + (size_t)which * (DM * DM);

    const int m0 = blockIdx.x * 128;
    const int n0 = blockIdx.y * 128;
    const int t = threadIdx.x, w = t >> 6, lane = t & 63;
    const int quad = lane >> 4, qr = lane & 15;
    const int arow = t >> 4;           // A staging: 16 rows/pass
    const int acol = (t & 15) * 4;     // float4 col
    const int brow = t >> 3;           // B staging: 32 rows/pass
    const int bcol = (t & 7) * 8;      // ushort8 col
    const int mw = 64 * (w >> 1), nw = 64 * (w & 1);

    floatx4 acc[4][4] = {};
    float4  areg[8];
    ushort8 breg[4];

    #pragma unroll
    for (int i = 0; i < 8; ++i)
        areg[i] = *(const float4*)(X + (size_t)(m0 + i * 16 + arow) * DM + acol);
    #pragma unroll
    for (int i = 0; i < 4; ++i)
        breg[i] = *(const ushort8*)(Bt + (size_t)(n0 + i * 32 + brow) * DM + bcol);

    for (int k0 = 0; k0 < DM; k0 += 64) {
        __syncthreads();
        #pragma unroll
        for (int i = 0; i < 8; ++i) {
            uint2 o;
            o.x = pack2bf(areg[i].x, areg[i].y);
            o.y = pack2bf(areg[i].z, areg[i].w);
            *(uint2*)&As[i * 16 + arow][acol] = o;
        }
        #pragma unroll
        for (int i = 0; i < 4; ++i)
            *(ushort8*)&Bs[i * 32 + brow][bcol] = breg[i];
        __syncthreads();

        if (k0 + 64 < DM) {
            #pragma unroll
            for (int i = 0; i < 8; ++i)
                areg[i] = *(const float4*)(X + (size_t)(m0 + i * 16 + arow) * DM + k0 + 64 + acol);
            #pragma unroll
            for (int i = 0; i < 4; ++i)
                breg[i] = *(const ushort8*)(Bt + (size_t)(n0 + i * 32 + brow) * DM + k0 + 64 + bcol);
        }

        #pragma unroll
        for (int kh = 0; kh < 2; ++kh) {
            short8 af[4], bf[4];
            #pragma unroll
            for (int si = 0; si < 4; ++si)
                af[si] = *(const short8*)&As[mw + 16 * si + qr][kh * 32 + quad * 8];
            #pragma unroll
            for (int sj = 0; sj < 4; ++sj)
                bf[sj] = *(const short8*)&Bs[nw + 16 * sj + qr][kh * 32 + quad * 8];
            #pragma unroll
            for (int si = 0; si < 4; ++si)
                #pragma unroll
                for (int sj = 0; sj < 4; ++sj)
                    acc[si][sj] = __builtin_amdgcn_mfma_f32_16x16x32_bf16(
                        af[si], bf[sj], acc[si][sj], 0, 0, 0);
        }
    }

    if (which == 0) {
        #pragma unroll
        for (int si = 0; si < 4; ++si) {
            #pragma unroll
            for (int sj = 0; sj < 4; ++sj) {
                const int col = n0 + nw + 16 * sj + qr;
                const int h = col >> 6, d = col & 63;
                #pragma unroll
                for (int r = 0; r < 4; ++r) {
                    const int row = m0 + mw + 16 * si + quad * 4 + r;
                    const int b = row >> 11, s = row & (SEQ - 1);
                    Oq[((size_t)(b * NH + h) * SEQ + s) * DQ + d] = f2bf(acc[si][sj][r] * QSCALE);
                }
            }
        }
    } else if (which == 1) {
        #pragma unroll
        for (int si = 0; si < 4; ++si) {
            #pragma unroll
            for (int sj = 0; sj < 4; ++sj) {
                const int col = n0 + nw + 16 * sj + qr;
                const int h = col >> 6, d = col & 63;
                #pragma unroll
                for (int r = 0; r < 4; ++r) {
                    const int row = m0 + mw + 16 * si + quad * 4 + r;
                    const int b = row >> 11, s = row & (SEQ - 1);
                    // Kf fragment-major
                    Ok[(size_t)(b * NH + h) * (SEQ * DQ)
                       + (size_t)(((s >> 5) * 4 + (d >> 4)) << 9)
                       + ((((d >> 3) & 1) << 5) + (s & 31)) * 8 + (d & 7)] = f2bf(acc[si][sj][r]);
                }
            }
        }
    } else {
        #pragma unroll
        for (int si = 0; si < 4; ++si) {
            #pragma unroll
            for (int sj = 0; sj < 4; ++sj) {
                const int col = n0 + nw + 16 * sj + qr;
                const int h = col >> 6, d = col & 63;
                #pragma unroll
                for (int r = 0; r < 4; ++r) {
                    const int row = m0 + mw + 16 * si + quad * 4 + r;
                    const int b = row >> 11, s = row & (SEQ - 1);
                    // Vf fragment-major
                    Ovt[(size_t)(b * NH + h) * (SEQ * DQ)
                        + (size_t)((s >> 6) << 12) + (((s >> 5) & 1) << 11)
                        + ((d >> 5) << 10) + (((s >> 4) & 1) << 9)
                        + ((((s >> 3) & 1) << 5) + (d & 31)) * 8 + (s & 7)] = f2bf(acc[si][sj][r]);
                }
            }
        }
    }
}

// ---------------------------------------------------------------------------
// out GEMM: 64x128 tile (512 blocks = 2/CU), BK=64, register-prefetched.
// ---------------------------------------------------------------------------
__global__ __launch_bounds__(256) void out_gemm_kernel(
    const unsigned short* __restrict__ A, const unsigned short* __restrict__ Bt,
    float* __restrict__ C)
{
    __shared__ unsigned short As[64][APAD];
    __shared__ unsigned short Bs[128][APAD];

    const int m0 = blockIdx.x * 64;
    const int n0 = blockIdx.y * 128;
    const int t = threadIdx.x, w = t >> 6, lane = t & 63;
    const int quad = lane >> 4, qr = lane & 15;
    const int brow = t >> 3;           // 32 rows/pass
    const int bcol = (t & 7) * 8;
    const int mw = 32 * (w >> 1), nw = 64 * (w & 1);

    floatx4 acc[2][4] = {};
    ushort8 areg[2], breg[4];

    #pragma unroll
    for (int i = 0; i < 2; ++i)
        areg[i] = *(const ushort8*)(A + (size_t)(m0 + i * 32 + brow) * DM + bcol);
    #pragma unroll
    for (int i = 0; i < 4; ++i)
        breg[i] = *(const ushort8*)(Bt + (size_t)(n0 + i * 32 + brow) * DM + bcol);

    for (int k0 = 0; k0 < DM; k0 += 64) {
        __syncthreads();
        #pragma unroll
        for (int i = 0; i < 2; ++i)
            *(ushort8*)&As[i * 32 + brow][bcol] = areg[i];
        #pragma unroll
        for (int i = 0; i < 4; ++i)
            *(ushort8*)&Bs[i * 32 + brow][bcol] = breg[i];
        __syncthreads();

        if (k0 + 64 < DM) {
            #pragma unroll
            for (int i = 0; i < 2; ++i)
                areg[i] = *(const ushort8*)(A + (size_t)(m0 + i * 32 + brow) * DM + k0 + 64 + bcol);
            #pragma unroll
            for (int i = 0; i < 4; ++i)
                breg[i] = *(const ushort8*)(Bt + (size_t)(n0 + i * 32 + brow) * DM + k0 + 64 + bcol);
        }

        #pragma unroll
        for (int kh = 0; kh < 2; ++kh) {
            short8 af[2], bf[4];
            #pragma unroll
            for (int si = 0; si < 2; ++si)
                af[si] = *(const short8*)&As[mw + 16 * si + qr][kh * 32 + quad * 8];
            #pragma unroll
            for (int sj = 0; sj < 4; ++sj)
                bf[sj] = *(const short8*)&Bs[nw + 16 * sj + qr][kh * 32 + quad * 8];
            #pragma unroll
            for (int si = 0; si < 2; ++si)
                #pragma unroll
                for (int sj = 0; sj < 4; ++sj)
                    acc[si][sj] = __builtin_amdgcn_mfma_f32_16x16x32_bf16(
                        af[si], bf[sj], acc[si][sj], 0, 0, 0);
        }
    }

    #pragma unroll
    for (int si = 0; si < 2; ++si) {
        #pragma unroll
        for (int sj = 0; sj < 4; ++sj) {
            const int col = n0 + nw + 16 * sj + qr;
            #pragma unroll
            for (int r = 0; r < 4; ++r) {
                const int row = m0 + mw + 16 * si + quad * 4 + r;
                C[(size_t)row * DM + col] = acc[si][sj][r];
            }
        }
    }
}

// ---------------------------------------------------------------------------
// flash attention v11: fragment-major K/V -> register-direct loop, ZERO
// in-loop LDS and ZERO in-loop barriers.
// v10 post-mortem: barrier removal was neutral (54.8 vs 54.2 us); the real
// structural cost is phase-locked waves: all 4 waves do QK together, softmax
// together, PV together -> VALU (softmax, ~45% busy) and MFMA (~26%) pipes
// used alternately, never concurrently. Pipe-sum floor ~25-30 us.
// v9 proved barrier-free works but fragment loads at 128B stride touched 32
// lines/wave-load (L1 transaction bound, 130 us). v11 fixes the layout:
// qkv_gemm stores K/V in MFMA-fragment order so every fragment load is
// base + lane*16 -- contiguous 1KB/wave, 4 cache lines, L2-resident (v8
// FETCH=12MB proof), L1-shared across waves. Waves free-run and stagger ->
// exp2 of one wave overlaps MFMA of another; setprio arbitrates (m191).
// Reg-prefetch one tile ahead (ak after QK, bv after PV). LDS = 17.4 KB
// epilogue combine only. Kept: T1 XCD decode, T5 setprio, T12 permlane,
// kh-split + epilogue combine. grid = (1024), block 256.
// MFMA 32x32x16 layouts: A[m=lane&31][k=(lane>>5)*8+j],
// B[k=(lane>>5)*8+j][n=lane&31], C/D col=lane&31,
// row=(reg&3)+8*(reg>>2)+4*(lane>>5)  (HW-verified m74/m101).
// ---------------------------------------------------------------------------
__global__ __launch_bounds__(256, 4) void attn_kernel(
    const unsigned short* __restrict__ Qp, const unsigned short* __restrict__ Kf,
    const unsigned short* __restrict__ Vf, unsigned short* __restrict__ Hd)
{
    __shared__ float epi[64 * 66 + 128];   // Obuf 64x66 + lbuf: 17.4 KB

    // XCD-aware decode: xcd = f&7 (round-robin dispatch), each XCD owns
    // 4 complete bh-groups (1024 % 8 == 0 -> bijective).
    const int f    = blockIdx.x;
    const int xcd  = f & 7;
    const int slot = f >> 3;            // 0..127 within XCD
    const int tile = slot & 31;         // q-tile
    const int bhi  = (slot >> 5) * 8 + xcd;   // 0..31
    const int b = bhi >> 3, h = bhi & 7;

    const int s0 = tile * 64;
    const size_t bh   = (size_t)(b * NH + h);
    const size_t base = bh * SEQ * DQ;

    const int t    = threadIdx.x;
    const int w    = t >> 6;
    const int lane = t & 63;
    const int qh   = w >> 1;      // q-half (rows 32qh..32qh+31)
    const int kh   = w & 1;       // kv-half within each 64-kv tile
    const int ln31 = lane & 31;
    const int lh   = lane >> 5;   // lane half

    // ---- Q B-fragments direct from global (once): B[k=d][n=q] ----
    short8 bq[4];
    {
        const unsigned short* gq = Qp + base + (size_t)(s0 + 32 * qh + ln31) * DQ + lh * 8;
        #pragma unroll
        for (int s = 0; s < 4; ++s)
            bq[s] = *(const short8*)(gq + 16 * s);
    }

    // fragment-major stream pointers: everything is base + lane*16B
    const unsigned short* pK = Kf + base + ((size_t)kh << 11) + (size_t)lane * 8;
    const unsigned short* pV = Vf + base + ((size_t)kh << 11) + (size_t)lane * 8;

    floatx16 accO[2] = {};   // partial O[32q][64dv]: a=dv-block; lane col=dv
    float l_lane = 0.f;

    // ---- prologue: fragment loads for kt=0 ----
    short8 ak[4], bv[4];
    #pragma unroll
    for (int s = 0; s < 4; ++s)
        ak[s] = *(const short8*)(pK + s * 512);
    #pragma unroll
    for (int a = 0; a < 2; ++a)
        #pragma unroll
        for (int s = 0; s < 2; ++s)
            bv[a * 2 + s] = *(const short8*)(pV + a * 1024 + s * 512);

    for (int kt = 0; kt < SEQ; kt += 64) {
        // ---- S^T[32kv][32q] = K-half @ Q-half^T (4-chain over d=64) ----
        floatx16 z = {};
        __builtin_amdgcn_s_setprio(1);
        #pragma unroll
        for (int s = 0; s < 4; ++s)
            z = __builtin_amdgcn_mfma_f32_32x32x16_bf16(ak[s], bq[s], z, 0, 0, 0);
        __builtin_amdgcn_s_setprio(0);

        // ---- prefetch next ak (regs free after QK; lands during softmax+PV) ----
        const int ktn = (kt + 64 < SEQ) ? kt + 64 : kt;
        {
            const unsigned short* nK = pK + ((size_t)(ktn >> 5) << 11);
            #pragma unroll
            for (int s = 0; s < 4; ++s)
                ak[s] = *(const short8*)(nK + s * 512);
        }

        // ---- exp2, l accumulate, pack P (reg 4g+j -> kv = 8g+4lh+j) ----
        unsigned wg[4][2];
        #pragma unroll
        for (int g = 0; g < 4; ++g) {
            const float p0 = __builtin_amdgcn_exp2f(z[4 * g + 0]);
            const float p1 = __builtin_amdgcn_exp2f(z[4 * g + 1]);
            const float p2 = __builtin_amdgcn_exp2f(z[4 * g + 2]);
            const float p3 = __builtin_amdgcn_exp2f(z[4 * g + 3]);
            l_lane += (p0 + p1) + (p2 + p3);
            wg[g][0] = pack2bf(p0, p1);
            wg[g][1] = pack2bf(p2, p3);
        }

        // ---- T12: build PV A-fragments in-register via permlane32_swap ----
        const uintx2 e0 = __builtin_amdgcn_permlane32_swap(wg[0][0], wg[1][0], false, false);
        const uintx2 e1 = __builtin_amdgcn_permlane32_swap(wg[0][1], wg[1][1], false, false);
        const uintx2 e2 = __builtin_amdgcn_permlane32_swap(wg[2][0], wg[3][0], false, false);
        const uintx2 e3 = __builtin_amdgcn_permlane32_swap(wg[2][1], wg[3][1], false, false);
        uintx4 ua0, ua1;
        ua0[0] = e0[0]; ua0[1] = e1[0]; ua0[2] = e0[1]; ua0[3] = e1[1];
        ua1[0] = e2[0]; ua1[1] = e3[0]; ua1[2] = e2[1]; ua1[3] = e3[1];
        const short8 ap0 = __builtin_bit_cast(short8, ua0);
        const short8 ap1 = __builtin_bit_cast(short8, ua1);

        // ---- PV: accO[a] += P[32q][32kv] @ V[32kv][32dv] ----
        __builtin_amdgcn_s_setprio(1);
        #pragma unroll
        for (int a = 0; a < 2; ++a) {
            accO[a] = __builtin_amdgcn_mfma_f32_32x32x16_bf16(ap0, bv[a * 2 + 0], accO[a], 0, 0, 0);
            accO[a] = __builtin_amdgcn_mfma_f32_32x32x16_bf16(ap1, bv[a * 2 + 1], accO[a], 0, 0, 0);
        }
        __builtin_amdgcn_s_setprio(0);

        // ---- prefetch next bv (regs free after PV; lands by next PV) ----
        {
            const unsigned short* nV = pV + ((size_t)(ktn >> 6) << 12);
            #pragma unroll
            for (int a = 0; a < 2; ++a)
                #pragma unroll
                for (int s = 0; s < 2; ++s)
                    bv[a * 2 + s] = *(const short8*)(nV + a * 1024 + s * 512);
        }
    }

    // ---- cross-kh combine: O and l, via epilogue-only LDS ----
    float l2 = l_lane + __shfl_xor(l_lane, 32);   // full kv-half sum for q=32qh+ln31
    float* Obuf = epi;                 // 64x66 f32
    float* lbuf = epi + 64 * 66;       // [0..63] kh0-l, [64..127] inv_l

    if (kh == 0) {
        if (lane < 32) lbuf[qh * 32 + lane] = l2;
        #pragma unroll
        for (int a = 0; a < 2; ++a)
            #pragma unroll
            for (int r = 0; r < 16; ++r) {
                const int qrow = (r & 3) + 8 * (r >> 2) + 4 * lh;
                Obuf[(32 * qh + qrow) * 66 + 32 * a + ln31] = accO[a][r];
            }
    }
    __syncthreads();

    if (kh == 1) {
        const float ltot = l2 + lbuf[qh * 32 + ln31];
        if (lane < 32) lbuf[64 + qh * 32 + lane] = 1.0f / ltot;  // same-wave RAW
        #pragma unroll
        for (int a = 0; a < 2; ++a)
            #pragma unroll
            for (int r = 0; r < 16; ++r) {
                const int qrow = (r & 3) + 8 * (r >> 2) + 4 * lh;
                const float o = accO[a][r] + Obuf[(32 * qh + qrow) * 66 + 32 * a + ln31];
                const float iv = lbuf[64 + qh * 32 + qrow];
                Hd[base + (size_t)(s0 + 32 * qh + qrow) * DQ + 32 * a + ln31] = f2bf(o * iv);
            }
    }
}

// ---------------------------------------------------------------------------
// kernel_launch
// Workspace (ushort units):
//   wt:    0        (3 x 262144)    qkv weights bf16, B^T [h*64+d][dd]
//   wo:    786432   (262144)        Wout bf16 [o][c]
//   q_ws:  1048576  (4194304)       q*QSCALE bf16 [b,h,s,d]
//   k_ws:  5242880  (4194304)       k bf16 fragment-major Kf
//   vt_ws: 9437184  (4194304)       v bf16 fragment-major Vf
//   h_ws:  13631488 (4194304)       heads bf16 (flat GEMM-A view)
// total ~34 MB
// ---------------------------------------------------------------------------
extern "C" void kernel_launch(void* const* d_in, const int* in_sizes, int n_in,
                              void* d_out, int out_size, void* d_ws, size_t ws_size,
                              hipStream_t stream) {
    const float* xq = (const float*)d_in[0];
    const float* xk = (const float*)d_in[1];
    const float* xv = (const float*)d_in[2];
    const float* Qw = (const float*)d_in[3];
    const float* Kw = (const float*)d_in[4];
    const float* Vw = (const float*)d_in[5];
    const float* Wo = (const float*)d_in[6];
    float* out = (float*)d_out;

    unsigned short* ws = (unsigned short*)d_ws;
    unsigned short* wt    = ws;
    unsigned short* wo    = ws + (size_t)786432;
    unsigned short* q_ws  = ws + (size_t)1048576;
    unsigned short* k_ws  = ws + (size_t)5242880;
    unsigned short* vt_ws = ws + (size_t)9437184;
    unsigned short* h_ws  = ws + (size_t)13631488;

    convert_w_kernel<<<dim3(256, 4), 256, 0, stream>>>(Qw, Kw, Vw, Wo, wt, wo);
    qkv_gemm_kernel<<<dim3(64, 4, 3), 256, 0, stream>>>(xq, xk, xv, wt, q_ws, k_ws, vt_ws);
    attn_kernel<<<dim3(1024), 256, 0, stream>>>(q_ws, k_ws, vt_ws, h_ws);
    out_gemm_kernel<<<dim3(128, 4), 256, 0, stream>>>(h_ws, wo, out);
}

// Round 6
// 177.553 us; speedup vs baseline: 1.4363x; 1.0218x over previous
//
#include <hip/hip_runtime.h>
#include <math.h>

// Problem constants (B=4, S=2048, D_MODEL=512, H=8, DQ=64)
#define BATCH 4
#define SEQ   2048
#define DM    512
#define NH    8
#define DQ    64
#define BS    (BATCH*SEQ)     // 8192 rows
#define APAD  72              // padded tile stride in gemms

// q pre-scale: 1/sqrt(64) * log2(e), so softmax uses native 2^x (v_exp_f32)
#define QSCALE 0.18033688011112042f

typedef short  short8   __attribute__((ext_vector_type(8)));
typedef float  floatx4  __attribute__((ext_vector_type(4)));
typedef float  floatx16 __attribute__((ext_vector_type(16)));
typedef unsigned short ushort8 __attribute__((ext_vector_type(8)));
typedef unsigned uintx2 __attribute__((ext_vector_type(2)));
typedef unsigned uintx4 __attribute__((ext_vector_type(4)));

// cheap bf16: round-half-up (1 add + shift). Ties-only delta vs RNE.
__device__ __forceinline__ unsigned short f2bf(float f) {
    return (unsigned short)((__float_as_uint(f) + 0x8000u) >> 16);
}
// pack two floats -> two bf16 in one u32 (lo = a, hi = b): 2 adds + 1 v_perm
__device__ __forceinline__ unsigned pack2bf(float a, float b) {
    unsigned ua = __float_as_uint(a) + 0x8000u;
    unsigned ub = __float_as_uint(b) + 0x8000u;
    return __builtin_amdgcn_perm(ub, ua, 0x07060302u);  // {ub[3],ub[2],ua[3],ua[2]}
}

// ---------------------------------------------------------------------------
// convert_w v12: COALESCED reads for the qkv projections.
// Old mapping had 64 lanes sharing one (h,d) with dd varying -> every 4-B
// load its own cache line. New mapping: consecutive lanes take consecutive
// n = h*64+d -> each of the 4 reads is a 256-B coalesced wave-load; the
// uint2 output store becomes an 8-B scatter (stride 1 KB), which is
// fire-and-forget. which==3 (Wout) unchanged (both sides coalesced).
// grid (256, 4).
// ---------------------------------------------------------------------------
__global__ __launch_bounds__(256) void convert_w_kernel(
    const float* __restrict__ Wq, const float* __restrict__ Wk,
    const float* __restrict__ Wv, const float* __restrict__ Wo,
    unsigned short* __restrict__ wt, unsigned short* __restrict__ wo)
{
    const int which = blockIdx.y;
    const int idx = blockIdx.x * 256 + threadIdx.x;   // 65536 per matrix
    if (which == 3) {
        float4 v = *(const float4*)(Wo + (size_t)idx * 4);
        uint2 o;
        o.x = pack2bf(v.x, v.y);
        o.y = pack2bf(v.z, v.w);
        *(uint2*)(wo + (size_t)idx * 4) = o;
    } else {
        const float* W = (which == 0) ? Wq : (which == 1) ? Wk : Wv;
        const int n   = idx & 511;         // h*64+d  (consecutive per lane)
        const int dd0 = (idx >> 9) * 4;    // 0..508
        const int h = n >> 6, d = n & 63;
        uint2 o;
        o.x = pack2bf(W[((size_t)h * DM + dd0 + 0) * DQ + d],
                      W[((size_t)h * DM + dd0 + 1) * DQ + d]);
        o.y = pack2bf(W[((size_t)h * DM + dd0 + 2) * DQ + d],
                      W[((size_t)h * DM + dd0 + 3) * DQ + d]);
        *(uint2*)(wt + (size_t)which * (DM * DM) + (size_t)n * DM + dd0) = o;
    }
}

// ---------------------------------------------------------------------------
// qkv GEMM v12: 64x128 tile (was 128x128), BK=64, K=512 (8 k-steps).
// Occupancy fix: acc 64->32, areg 32->16 VGPRs -> ~100 total -> 128-class ->
// 16 waves/CU = 4 blocks/CU (was 2 at VGPR~130). Grid 1536 = 6/CU queued.
// Same-A-strip n-blocks are 128 apart in block id -> same XCD -> A L2-shared.
// A (fp32 x, packed to bf16 at store) and B (bf16 weights) register-
// prefetched across the barrier. Outputs:
//   which 0 -> q*QSCALE bf16 [b,h,s,d]
//   which 1 -> k bf16 FRAGMENT-MAJOR Kf  [bh][s>>5][d>>4][lane][8]
//   which 2 -> v bf16 FRAGMENT-MAJOR Vf  [bh][s>>6][(s>>5)&1][d>>5][(s>>4)&1][lane][8]
// grid (128, 4, 3), block 256 (4 waves, 2x2; wave tile 32x64).
// ---------------------------------------------------------------------------
__global__ __launch_bounds__(256) void qkv_gemm_kernel(
    const float* __restrict__ Xq, const float* __restrict__ Xk,
    const float* __restrict__ Xv, const unsigned short* __restrict__ wt,
    unsigned short* __restrict__ Oq, unsigned short* __restrict__ Ok,
    unsigned short* __restrict__ Ovt)
{
    __shared__ unsigned short As[64][APAD];
    __shared__ unsigned short Bs[128][APAD];

    const int which = blockIdx.z;
    const float* X = (which == 0) ? Xq : (which == 1) ? Xk : Xv;
    const unsigned short* Bt = wt + (size_t)which * (DM * DM);

    const int m0 = blockIdx.x * 64;
    const int n0 = blockIdx.y * 128;
    const int t = threadIdx.x, w = t >> 6, lane = t & 63;
    const int quad = lane >> 4, qr = lane & 15;
    const int arow = t >> 4;           // A staging: 16 rows/pass, 4 passes
    const int acol = (t & 15) * 4;     // float4 col
    const int brow = t >> 3;           // B staging: 32 rows/pass, 4 passes
    const int bcol = (t & 7) * 8;      // ushort8 col
    const int mw = 32 * (w >> 1), nw = 64 * (w & 1);

    floatx4 acc[2][4] = {};
    float4  areg[4];
    ushort8 breg[4];

    #pragma unroll
    for (int i = 0; i < 4; ++i)
        areg[i] = *(const float4*)(X + (size_t)(m0 + i * 16 + arow) * DM + acol);
    #pragma unroll
    for (int i = 0; i < 4; ++i)
        breg[i] = *(const ushort8*)(Bt + (size_t)(n0 + i * 32 + brow) * DM + bcol);

    for (int k0 = 0; k0 < DM; k0 += 64) {
        __syncthreads();
        #pragma unroll
        for (int i = 0; i < 4; ++i) {
            uint2 o;
            o.x = pack2bf(areg[i].x, areg[i].y);
            o.y = pack2bf(areg[i].z, areg[i].w);
            *(uint2*)&As[i * 16 + arow][acol] = o;
        }
        #pragma unroll
        for (int i = 0; i < 4; ++i)
            *(ushort8*)&Bs[i * 32 + brow][bcol] = breg[i];
        __syncthreads();

        if (k0 + 64 < DM) {
            #pragma unroll
            for (int i = 0; i < 4; ++i)
                areg[i] = *(const float4*)(X + (size_t)(m0 + i * 16 + arow) * DM + k0 + 64 + acol);
            #pragma unroll
            for (int i = 0; i < 4; ++i)
                breg[i] = *(const ushort8*)(Bt + (size_t)(n0 + i * 32 + brow) * DM + k0 + 64 + bcol);
        }

        #pragma unroll
        for (int kh = 0; kh < 2; ++kh) {
            short8 af[2], bf[4];
            #pragma unroll
            for (int si = 0; si < 2; ++si)
                af[si] = *(const short8*)&As[mw + 16 * si + qr][kh * 32 + quad * 8];
            #pragma unroll
            for (int sj = 0; sj < 4; ++sj)
                bf[sj] = *(const short8*)&Bs[nw + 16 * sj + qr][kh * 32 + quad * 8];
            #pragma unroll
            for (int si = 0; si < 2; ++si)
                #pragma unroll
                for (int sj = 0; sj < 4; ++sj)
                    acc[si][sj] = __builtin_amdgcn_mfma_f32_16x16x32_bf16(
                        af[si], bf[sj], acc[si][sj], 0, 0, 0);
        }
    }

    if (which == 0) {
        #pragma unroll
        for (int si = 0; si < 2; ++si) {
            #pragma unroll
            for (int sj = 0; sj < 4; ++sj) {
                const int col = n0 + nw + 16 * sj + qr;
                const int h = col >> 6, d = col & 63;
                #pragma unroll
                for (int r = 0; r < 4; ++r) {
                    const int row = m0 + mw + 16 * si + quad * 4 + r;
                    const int b = row >> 11, s = row & (SEQ - 1);
                    Oq[((size_t)(b * NH + h) * SEQ + s) * DQ + d] = f2bf(acc[si][sj][r] * QSCALE);
                }
            }
        }
    } else if (which == 1) {
        #pragma unroll
        for (int si = 0; si < 2; ++si) {
            #pragma unroll
            for (int sj = 0; sj < 4; ++sj) {
                const int col = n0 + nw + 16 * sj + qr;
                const int h = col >> 6, d = col & 63;
                #pragma unroll
                for (int r = 0; r < 4; ++r) {
                    const int row = m0 + mw + 16 * si + quad * 4 + r;
                    const int b = row >> 11, s = row & (SEQ - 1);
                    // Kf fragment-major
                    Ok[(size_t)(b * NH + h) * (SEQ * DQ)
                       + (size_t)(((s >> 5) * 4 + (d >> 4)) << 9)
                       + ((((d >> 3) & 1) << 5) + (s & 31)) * 8 + (d & 7)] = f2bf(acc[si][sj][r]);
                }
            }
        }
    } else {
        #pragma unroll
        for (int si = 0; si < 2; ++si) {
            #pragma unroll
            for (int sj = 0; sj < 4; ++sj) {
                const int col = n0 + nw + 16 * sj + qr;
                const int h = col >> 6, d = col & 63;
                #pragma unroll
                for (int r = 0; r < 4; ++r) {
                    const int row = m0 + mw + 16 * si + quad * 4 + r;
                    const int b = row >> 11, s = row & (SEQ - 1);
                    // Vf fragment-major
                    Ovt[(size_t)(b * NH + h) * (SEQ * DQ)
                        + (size_t)((s >> 6) << 12) + (((s >> 5) & 1) << 11)
                        + ((d >> 5) << 10) + (((s >> 4) & 1) << 9)
                        + ((((s >> 3) & 1) << 5) + (d & 31)) * 8 + (s & 7)] = f2bf(acc[si][sj][r]);
                }
            }
        }
    }
}

// ---------------------------------------------------------------------------
// out GEMM v12: 64x64 tile (was 64x128), grid (128,8) = 1024 blocks ->
// 4 blocks/CU (was 2). acc 16 VGPR, wave tile 32x32. Same-A n-blocks are
// 128 apart in id -> same XCD -> A strips L2-shared. BK=64, reg-prefetched.
// ---------------------------------------------------------------------------
__global__ __launch_bounds__(256) void out_gemm_kernel(
    const unsigned short* __restrict__ A, const unsigned short* __restrict__ Bt,
    float* __restrict__ C)
{
    __shared__ unsigned short As[64][APAD];
    __shared__ unsigned short Bs[64][APAD];

    const int m0 = blockIdx.x * 64;
    const int n0 = blockIdx.y * 64;
    const int t = threadIdx.x, w = t >> 6, lane = t & 63;
    const int quad = lane >> 4, qr = lane & 15;
    const int brow = t >> 3;           // 32 rows/pass, 2 passes
    const int bcol = (t & 7) * 8;
    const int mw = 32 * (w >> 1), nw = 32 * (w & 1);

    floatx4 acc[2][2] = {};
    ushort8 areg[2], breg[2];

    #pragma unroll
    for (int i = 0; i < 2; ++i) {
        areg[i] = *(const ushort8*)(A + (size_t)(m0 + i * 32 + brow) * DM + bcol);
        breg[i] = *(const ushort8*)(Bt + (size_t)(n0 + i * 32 + brow) * DM + bcol);
    }

    for (int k0 = 0; k0 < DM; k0 += 64) {
        __syncthreads();
        #pragma unroll
        for (int i = 0; i < 2; ++i) {
            *(ushort8*)&As[i * 32 + brow][bcol] = areg[i];
            *(ushort8*)&Bs[i * 32 + brow][bcol] = breg[i];
        }
        __syncthreads();

        if (k0 + 64 < DM) {
            #pragma unroll
            for (int i = 0; i < 2; ++i) {
                areg[i] = *(const ushort8*)(A + (size_t)(m0 + i * 32 + brow) * DM + k0 + 64 + bcol);
                breg[i] = *(const ushort8*)(Bt + (size_t)(n0 + i * 32 + brow) * DM + k0 + 64 + bcol);
            }
        }

        #pragma unroll
        for (int kh = 0; kh < 2; ++kh) {
            short8 af[2], bf[2];
            #pragma unroll
            for (int si = 0; si < 2; ++si)
                af[si] = *(const short8*)&As[mw + 16 * si + qr][kh * 32 + quad * 8];
            #pragma unroll
            for (int sj = 0; sj < 2; ++sj)
                bf[sj] = *(const short8*)&Bs[nw + 16 * sj + qr][kh * 32 + quad * 8];
            #pragma unroll
            for (int si = 0; si < 2; ++si)
                #pragma unroll
                for (int sj = 0; sj < 2; ++sj)
                    acc[si][sj] = __builtin_amdgcn_mfma_f32_16x16x32_bf16(
                        af[si], bf[sj], acc[si][sj], 0, 0, 0);
        }
    }

    #pragma unroll
    for (int si = 0; si < 2; ++si) {
        #pragma unroll
        for (int sj = 0; sj < 2; ++sj) {
            const int col = n0 + nw + 16 * sj + qr;
            #pragma unroll
            for (int r = 0; r < 4; ++r) {
                const int row = m0 + mw + 16 * si + quad * 4 + r;
                C[(size_t)row * DM + col] = acc[si][sj][r];
            }
        }
    }
}

// ---------------------------------------------------------------------------
// flash attention v11 (unchanged this round): fragment-major K/V ->
// register-direct loop, zero in-loop LDS/barriers. 52.3 us, MfmaUtil 28%,
// conflicts 0, FETCH 12.3 MB. Occupancy capped at 16 waves/CU by unified
// VGPR+AGPR ~92 (m69 class). grid = (1024), block 256.
// MFMA 32x32x16 layouts: A[m=lane&31][k=(lane>>5)*8+j],
// B[k=(lane>>5)*8+j][n=lane&31], C/D col=lane&31,
// row=(reg&3)+8*(reg>>2)+4*(lane>>5)  (HW-verified m74/m101).
// ---------------------------------------------------------------------------
__global__ __launch_bounds__(256, 4) void attn_kernel(
    const unsigned short* __restrict__ Qp, const unsigned short* __restrict__ Kf,
    const unsigned short* __restrict__ Vf, unsigned short* __restrict__ Hd)
{
    __shared__ float epi[64 * 66 + 128];   // Obuf 64x66 + lbuf: 17.4 KB

    // XCD-aware decode: xcd = f&7 (round-robin dispatch), each XCD owns
    // 4 complete bh-groups (1024 % 8 == 0 -> bijective).
    const int f    = blockIdx.x;
    const int xcd  = f & 7;
    const int slot = f >> 3;            // 0..127 within XCD
    const int tile = slot & 31;         // q-tile
    const int bhi  = (slot >> 5) * 8 + xcd;   // 0..31
    const int b = bhi >> 3, h = bhi & 7;

    const int s0 = tile * 64;
    const size_t bh   = (size_t)(b * NH + h);
    const size_t base = bh * SEQ * DQ;

    const int t    = threadIdx.x;
    const int w    = t >> 6;
    const int lane = t & 63;
    const int qh   = w >> 1;      // q-half (rows 32qh..32qh+31)
    const int kh   = w & 1;       // kv-half within each 64-kv tile
    const int ln31 = lane & 31;
    const int lh   = lane >> 5;   // lane half

    // ---- Q B-fragments direct from global (once): B[k=d][n=q] ----
    short8 bq[4];
    {
        const unsigned short* gq = Qp + base + (size_t)(s0 + 32 * qh + ln31) * DQ + lh * 8;
        #pragma unroll
        for (int s = 0; s < 4; ++s)
            bq[s] = *(const short8*)(gq + 16 * s);
    }

    // fragment-major stream pointers: everything is base + lane*16B
    const unsigned short* pK = Kf + base + ((size_t)kh << 11) + (size_t)lane * 8;
    const unsigned short* pV = Vf + base + ((size_t)kh << 11) + (size_t)lane * 8;

    floatx16 accO[2] = {};   // partial O[32q][64dv]: a=dv-block; lane col=dv
    float l_lane = 0.f;

    // ---- prologue: fragment loads for kt=0 ----
    short8 ak[4], bv[4];
    #pragma unroll
    for (int s = 0; s < 4; ++s)
        ak[s] = *(const short8*)(pK + s * 512);
    #pragma unroll
    for (int a = 0; a < 2; ++a)
        #pragma unroll
        for (int s = 0; s < 2; ++s)
            bv[a * 2 + s] = *(const short8*)(pV + a * 1024 + s * 512);

    for (int kt = 0; kt < SEQ; kt += 64) {
        // ---- S^T[32kv][32q] = K-half @ Q-half^T (4-chain over d=64) ----
        floatx16 z = {};
        __builtin_amdgcn_s_setprio(1);
        #pragma unroll
        for (int s = 0; s < 4; ++s)
            z = __builtin_amdgcn_mfma_f32_32x32x16_bf16(ak[s], bq[s], z, 0, 0, 0);
        __builtin_amdgcn_s_setprio(0);

        // ---- prefetch next ak (regs free after QK; lands during softmax+PV) ----
        const int ktn = (kt + 64 < SEQ) ? kt + 64 : kt;
        {
            const unsigned short* nK = pK + ((size_t)(ktn >> 5) << 11);
            #pragma unroll
            for (int s = 0; s < 4; ++s)
                ak[s] = *(const short8*)(nK + s * 512);
        }

        // ---- exp2, l accumulate, pack P (reg 4g+j -> kv = 8g+4lh+j) ----
        unsigned wg[4][2];
        #pragma unroll
        for (int g = 0; g < 4; ++g) {
            const float p0 = __builtin_amdgcn_exp2f(z[4 * g + 0]);
            const float p1 = __builtin_amdgcn_exp2f(z[4 * g + 1]);
            const float p2 = __builtin_amdgcn_exp2f(z[4 * g + 2]);
            const float p3 = __builtin_amdgcn_exp2f(z[4 * g + 3]);
            l_lane += (p0 + p1) + (p2 + p3);
            wg[g][0] = pack2bf(p0, p1);
            wg[g][1] = pack2bf(p2, p3);
        }

        // ---- T12: build PV A-fragments in-register via permlane32_swap ----
        const uintx2 e0 = __builtin_amdgcn_permlane32_swap(wg[0][0], wg[1][0], false, false);
        const uintx2 e1 = __builtin_amdgcn_permlane32_swap(wg[0][1], wg[1][1], false, false);
        const uintx2 e2 = __builtin_amdgcn_permlane32_swap(wg[2][0], wg[3][0], false, false);
        const uintx2 e3 = __builtin_amdgcn_permlane32_swap(wg[2][1], wg[3][1], false, false);
        uintx4 ua0, ua1;
        ua0[0] = e0[0]; ua0[1] = e1[0]; ua0[2] = e0[1]; ua0[3] = e1[1];
        ua1[0] = e2[0]; ua1[1] = e3[0]; ua1[2] = e2[1]; ua1[3] = e3[1];
        const short8 ap0 = __builtin_bit_cast(short8, ua0);
        const short8 ap1 = __builtin_bit_cast(short8, ua1);

        // ---- PV: accO[a] += P[32q][32kv] @ V[32kv][32dv] ----
        __builtin_amdgcn_s_setprio(1);
        #pragma unroll
        for (int a = 0; a < 2; ++a) {
            accO[a] = __builtin_amdgcn_mfma_f32_32x32x16_bf16(ap0, bv[a * 2 + 0], accO[a], 0, 0, 0);
            accO[a] = __builtin_amdgcn_mfma_f32_32x32x16_bf16(ap1, bv[a * 2 + 1], accO[a], 0, 0, 0);
        }
        __builtin_amdgcn_s_setprio(0);

        // ---- prefetch next bv (regs free after PV; lands by next PV) ----
        {
            const unsigned short* nV = pV + ((size_t)(ktn >> 6) << 12);
            #pragma unroll
            for (int a = 0; a < 2; ++a)
                #pragma unroll
                for (int s = 0; s < 2; ++s)
                    bv[a * 2 + s] = *(const short8*)(nV + a * 1024 + s * 512);
        }
    }

    // ---- cross-kh combine: O and l, via epilogue-only LDS ----
    float l2 = l_lane + __shfl_xor(l_lane, 32);   // full kv-half sum for q=32qh+ln31
    float* Obuf = epi;                 // 64x66 f32
    float* lbuf = epi + 64 * 66;       // [0..63] kh0-l, [64..127] inv_l

    if (kh == 0) {
        if (lane < 32) lbuf[qh * 32 + lane] = l2;
        #pragma unroll
        for (int a = 0; a < 2; ++a)
            #pragma unroll
            for (int r = 0; r < 16; ++r) {
                const int qrow = (r & 3) + 8 * (r >> 2) + 4 * lh;
                Obuf[(32 * qh + qrow) * 66 + 32 * a + ln31] = accO[a][r];
            }
    }
    __syncthreads();

    if (kh == 1) {
        const float ltot = l2 + lbuf[qh * 32 + ln31];
        if (lane < 32) lbuf[64 + qh * 32 + lane] = 1.0f / ltot;  // same-wave RAW
        #pragma unroll
        for (int a = 0; a < 2; ++a)
            #pragma unroll
            for (int r = 0; r < 16; ++r) {
                const int qrow = (r & 3) + 8 * (r >> 2) + 4 * lh;
                const float o = accO[a][r] + Obuf[(32 * qh + qrow) * 66 + 32 * a + ln31];
                const float iv = lbuf[64 + qh * 32 + qrow];
                Hd[base + (size_t)(s0 + 32 * qh + qrow) * DQ + 32 * a + ln31] = f2bf(o * iv);
            }
    }
}

// ---------------------------------------------------------------------------
// kernel_launch
// Workspace (ushort units):
//   wt:    0        (3 x 262144)    qkv weights bf16, B^T [h*64+d][dd]
//   wo:    786432   (262144)        Wout bf16 [o][c]
//   q_ws:  1048576  (4194304)       q*QSCALE bf16 [b,h,s,d]
//   k_ws:  5242880  (4194304)       k bf16 fragment-major Kf
//   vt_ws: 9437184  (4194304)       v bf16 fragment-major Vf
//   h_ws:  13631488 (4194304)       heads bf16 (flat GEMM-A view)
// total ~34 MB
// ---------------------------------------------------------------------------
extern "C" void kernel_launch(void* const* d_in, const int* in_sizes, int n_in,
                              void* d_out, int out_size, void* d_ws, size_t ws_size,
                              hipStream_t stream) {
    const float* xq = (const float*)d_in[0];
    const float* xk = (const float*)d_in[1];
    const float* xv = (const float*)d_in[2];
    const float* Qw = (const float*)d_in[3];
    const float* Kw = (const float*)d_in[4];
    const float* Vw = (const float*)d_in[5];
    const float* Wo = (const float*)d_in[6];
    float* out = (float*)d_out;

    unsigned short* ws = (unsigned short*)d_ws;
    unsigned short* wt    = ws;
    unsigned short* wo    = ws + (size_t)786432;
    unsigned short* q_ws  = ws + (size_t)1048576;
    unsigned short* k_ws  = ws + (size_t)5242880;
    unsigned short* vt_ws = ws + (size_t)9437184;
    unsigned short* h_ws  = ws + (size_t)13631488;

    convert_w_kernel<<<dim3(256, 4), 256, 0, stream>>>(Qw, Kw, Vw, Wo, wt, wo);
    qkv_gemm_kernel<<<dim3(128, 4, 3), 256, 0, stream>>>(xq, xk, xv, wt, q_ws, k_ws, vt_ws);
    attn_kernel<<<dim3(1024), 256, 0, stream>>>(q_ws, k_ws, vt_ws, h_ws);
    out_gemm_kernel<<<dim3(128, 8), 256, 0, stream>>>(h_ws, wo, out);
}